// Round 14
// baseline (32.764 us; speedup 1.0000x reference)
//
#include <hip/hip_runtime.h>

#define NC 20
#define NCELL 49
#define NGT 32
#define NIMG 8192
#define PBLK 2048                  // blocks = 8 per CU exactly
#define TPB 4                      // tiles (images) per block: 8192/2048 exact
#define LAMBDA_COORD 5.0f
#define LAMBDA_NOOBJ 0.5f
#define EPS_IOU 1e-6f

// Tile = 1 image. Zero tail: every block does exactly 4 images. Persistent,
// double-buffered, issue-early/write-late staging (R12), shuffle-OR mask +
// single barrier per tile (R13). Compute body = R6 verbatim (thread=(cell,box),
// CE split across the box pair, S-form divide-free first-index argmax).
__global__ __launch_bounds__(128, 4) void yolo_main_kernel(
    const float* __restrict__ outputs,     // [N, 49, 30]
    const float* __restrict__ gt_boxes,    // [N, 32, 4]
    const int*   __restrict__ gt_labels,   // [N, 32]
    float* __restrict__ partials)          // [PBLK]
{
    __shared__ float2   s_act[2][736];     // 2 x 5888 B (49*15=735 float2, +1 pad)
    __shared__ float4   s_gtc[2][NGT];     // 2 x 512 B: x1,y1,x2,y2
    __shared__ float    s_ga [2][NGT];     // 2 x 128 B: gt area
    __shared__ unsigned s_mask[2];
    __shared__ float    s_w[2];

    const int tid = threadIdx.x;
    const int bid = blockIdx.x;

    float acc = 0.f;

    // prefetch registers (live across compute)
    float2 r0, r1, r2, r3, r4, r5;
    float4 gtr;
    unsigned labbit = 0u;

#define STAGE_ISSUE(img_) do {                                                \
    const float2* src_ = reinterpret_cast<const float2*>(outputs)             \
                       + (size_t)(img_) * 735;                                \
    r0 = src_[tid];                                                           \
    r1 = src_[tid + 128];                                                     \
    r2 = src_[tid + 256];                                                     \
    r3 = src_[tid + 384];                                                     \
    r4 = src_[tid + 512];                                                     \
    if (tid < 95) r5 = src_[tid + 640];                                       \
    if (tid < 32)                                                             \
        gtr = reinterpret_cast<const float4*>(gt_boxes)[(img_) * NGT + tid];  \
    else if (tid < 64)                                                        \
        labbit = 1u << gt_labels[(img_) * NGT + (tid - 32)];                  \
} while (0)

#define STAGE_WRITE(nb_) do {                                                 \
    s_act[nb_][tid]       = r0;                                               \
    s_act[nb_][tid + 128] = r1;                                               \
    s_act[nb_][tid + 256] = r2;                                               \
    s_act[nb_][tid + 384] = r3;                                               \
    s_act[nb_][tid + 512] = r4;                                               \
    if (tid < 95) s_act[nb_][tid + 640] = r5;                                 \
    if (tid < 32) {                                                           \
        s_gtc[nb_][tid] = make_float4(fmaf(gtr.z, -0.5f, gtr.x),              \
                                      fmaf(gtr.w, -0.5f, gtr.y),              \
                                      fmaf(gtr.z,  0.5f, gtr.x),              \
                                      fmaf(gtr.w,  0.5f, gtr.y));             \
        s_ga[nb_][tid] = gtr.z * gtr.w;                                       \
    } else if (tid < 64) {                                                    \
        unsigned m_ = labbit;                                                 \
        m_ |= __shfl_xor(m_, 1, 32);                                          \
        m_ |= __shfl_xor(m_, 2, 32);                                          \
        m_ |= __shfl_xor(m_, 4, 32);                                          \
        m_ |= __shfl_xor(m_, 8, 32);                                          \
        m_ |= __shfl_xor(m_, 16, 32);                                         \
        if (tid == 32) s_mask[nb_] = m_;                                      \
    }                                                                         \
} while (0)

    // ---- prologue: stage image bid into buffer 0 ----
    STAGE_ISSUE(bid);
    STAGE_WRITE(0);
    __syncthreads();                      // buffer 0 ready

    int cur = 0;
    #pragma unroll 1
    for (int k = 0; k < TPB; ++k) {
        const bool hn = (k + 1 < TPB);
        if (hn) STAGE_ISSUE(bid + (k + 1) * PBLK);

        // ============ compute image from buf[cur] (R6 body, single image) ====
        if (tid < 2 * NCELL) {
            const unsigned mask = s_mask[cur];
            const int p = tid & 1;
            const int s = tid >> 1;
            const float2* a2 = s_act[cur] + s * 15;

            // CE, split across the box pair (each thread: 10 classes)
            const float2* cp = a2 + 5 + p * 5;
            float2 c0 = cp[0], c1 = cp[1], c2 = cp[2], c3 = cp[3], c4 = cp[4];
            float mxh = fmaxf(fmaxf(fmaxf(c0.x, c0.y), fmaxf(c1.x, c1.y)),
                              fmaxf(fmaxf(c2.x, c2.y), fmaxf(c3.x, c3.y)));
            mxh = fmaxf(mxh, fmaxf(c4.x, c4.y));
            const unsigned mh = mask >> (p * 10);
            float selh = ((mh & 1u)   ? c0.x : 0.f) + ((mh & 2u)   ? c0.y : 0.f)
                       + ((mh & 4u)   ? c1.x : 0.f) + ((mh & 8u)   ? c1.y : 0.f)
                       + ((mh & 16u)  ? c2.x : 0.f) + ((mh & 32u)  ? c2.y : 0.f)
                       + ((mh & 64u)  ? c3.x : 0.f) + ((mh & 128u) ? c3.y : 0.f)
                       + ((mh & 256u) ? c4.x : 0.f) + ((mh & 512u) ? c4.y : 0.f);
            const float mx = fmaxf(mxh, __shfl_xor(mxh, 1));
            float ssh = __expf(c0.x - mx) + __expf(c0.y - mx)
                      + __expf(c1.x - mx) + __expf(c1.y - mx)
                      + __expf(c2.x - mx) + __expf(c2.y - mx)
                      + __expf(c3.x - mx) + __expf(c3.y - mx)
                      + __expf(c4.x - mx) + __expf(c4.y - mx);
            const float ssum = ssh + __shfl_xor(ssh, 1);
            const float sel  = selh + __shfl_xor(selh, 1);
            const float ce = (float)__popc(mask) * (mx + __logf(ssum)) - sel;

            // my box: floats [5p .. 5p+4] of the cell record
            float2 A = a2[2 * p], Bv = a2[2 * p + 1], Cv = a2[2 * p + 2];
            const float cx = p ? A.y  : A.x;
            const float cy = p ? Bv.x : A.y;
            const float w  = p ? Bv.y : Bv.x;
            const float h  = p ? Cv.x : Bv.y;
            const float cf = p ? Cv.y : Cv.x;

            const float px1 = fmaf(w, -0.5f, cx), py1 = fmaf(h, -0.5f, cy);
            const float px2 = fmaf(w,  0.5f, cx), py2 = fmaf(h,  0.5f, cy);
            const float pae = w * h + EPS_IOU;

            // IoU argmax over 32 GTs (broadcast LDS reads)
            const float4* gtc = s_gtc[cur];
            const float*  gab = s_ga[cur];
            float bin = -1.f, bS = 1.f;
            int bi = 0;
            #pragma unroll
            for (int j = 0; j < NGT; j += 2) {
                float4 g0 = gtc[j], g1 = gtc[j + 1];
                float2 ar = *reinterpret_cast<const float2*>(gab + j);
                {
                    float iw = fmaxf(fminf(px2, g0.z) - fmaxf(px1, g0.x), 0.f);
                    float ih = fmaxf(fminf(py2, g0.w) - fmaxf(py1, g0.y), 0.f);
                    float in = iw * ih, S = pae + ar.x;
                    if (in * bS > bin * S) { bin = in; bS = S; bi = j; }
                }
                {
                    float iw = fmaxf(fminf(px2, g1.z) - fmaxf(px1, g1.x), 0.f);
                    float ih = fmaxf(fminf(py2, g1.w) - fmaxf(py1, g1.y), 0.f);
                    float in = iw * ih, S = pae + ar.y;
                    if (in * bS > bin * S) { bin = in; bS = S; bi = j + 1; }
                }
            }

            float term;
            if (bin > 0.f) {
                float4 g = gtc[bi];
                const float iou = __fdividef(bin, bS - bin);
                const float dx = cx - (g.x + g.z) * 0.5f;
                const float dy = cy - (g.y + g.w) * 0.5f;
                const float dw = sqrtf(w) - sqrtf(g.z - g.x);
                const float dh = sqrtf(h) - sqrtf(g.w - g.y);
                term = LAMBDA_COORD * (dx * dx + dy * dy + dw * dw + dh * dh)
                     + (cf - iou) * (cf - iou) + ce;
            } else {
                term = LAMBDA_NOOBJ * cf * cf;
            }
            acc += term;
        }
        // =====================================================================

        if (hn) STAGE_WRITE(cur ^ 1);     // writes buf[cur^1] only: no conflict
        __syncthreads();                  // next buffer ready; cur reads done
        cur ^= 1;
    }

    // ---- block reduce (2 waves) -> 1 float per block ----
    #pragma unroll
    for (int o = 32; o > 0; o >>= 1)
        acc += __shfl_down(acc, o);
    if ((tid & 63) == 0) s_w[tid >> 6] = acc;
    __syncthreads();
    if (tid == 0)
        partials[bid] = s_w[0] + s_w[1];
}

__global__ __launch_bounds__(256) void yolo_reduce_kernel(
    const float* __restrict__ partials, float* __restrict__ out)
{
    float s = 0.f;
    #pragma unroll
    for (int k = 0; k < PBLK / 256; ++k)
        s += partials[threadIdx.x + k * 256];
    #pragma unroll
    for (int o = 32; o > 0; o >>= 1)
        s += __shfl_down(s, o);
    __shared__ float s_w[4];
    const int tid = threadIdx.x;
    if ((tid & 63) == 0) s_w[tid >> 6] = s;
    __syncthreads();
    if (tid == 0)
        out[0] = (s_w[0] + s_w[1] + s_w[2] + s_w[3]) * (1.0f / (float)NIMG);
}

extern "C" void kernel_launch(void* const* d_in, const int* in_sizes, int n_in,
                              void* d_out, int out_size, void* d_ws, size_t ws_size,
                              hipStream_t stream) {
    const float* outputs   = (const float*)d_in[0];
    const float* gt_boxes  = (const float*)d_in[1];
    const int*   gt_labels = (const int*)d_in[2];
    float* out      = (float*)d_out;
    float* partials = (float*)d_ws;          // PBLK floats = 8 KB

    yolo_main_kernel<<<PBLK, 128, 0, stream>>>(outputs, gt_boxes, gt_labels, partials);
    yolo_reduce_kernel<<<1, 256, 0, stream>>>(partials, out);
}

// Round 15
// 27.804 us; speedup vs baseline: 1.1784x; 1.1784x over previous
//
#include <hip/hip_runtime.h>

#define NC 20
#define NCELL 49
#define NGT 32
#define NIMG 8192
#define NTOT (NIMG * NCELL)        // 401408
#define CPB 128                    // cells per tile
#define NTILE (NTOT / CPB)         // 3136 tiles
#define PBLK 1024                  // persistent blocks = exactly 4 per CU
#define NSPAN 4                    // images spanned by 128 consecutive cells
#define LAMBDA_COORD 5.0f
#define LAMBDA_NOOBJ 0.5f
#define EPS_IOU 1e-6f

typedef _Float16 h2 __attribute__((ext_vector_type(2)));
#define H2MAX(a, b) __builtin_elementwise_max((a), (b))
#define H2MIN(a, b) __builtin_elementwise_min((a), (b))

// R13 structure (persistent, double-buffered, issue-early/write-late staging,
// shuffle-OR mask, one barrier per tile) with the IoU loop in PACKED FP16:
// GT staged as {min2,max2} fp16 records (8B/GT) + fp16 areas; geometry chain
// uses v_pk_min/max/add_f16 (full rate, 2 dims per instr). Compare chain in
// scalar fp16 (S-form, first-index tie-break). Epilogue/CE/loc stay f32 exact.
// Accuracy: fp16 IoU err ~1e-3 -> rare argmax flips; output err ~1-3 vs
// threshold 97.3 (2% of |out|~4864).
__global__ __launch_bounds__(256, 4) void yolo_main_kernel(
    const float* __restrict__ outputs,     // [N, 49, 30]
    const float* __restrict__ gt_boxes,    // [N, 32, 4]
    const int*   __restrict__ gt_labels,   // [N, 32]
    float* __restrict__ partials)          // [PBLK]
{
    __shared__ float4   s_act4[2][CPB * 30 / 4];   // 2 x 15360 B
    __shared__ float4   s_gtc[2][NSPAN * NGT];     // 2 x 2048 B (f32, epilogue)
    __shared__ uint2    s_gtp[2][NSPAN * NGT];     // 2 x 1024 B (fp16 {mn2,mx2})
    __shared__ _Float16 s_gah[2][NSPAN * NGT];     // 2 x  256 B (fp16 area)
    __shared__ unsigned s_mask[2][NSPAN];
    __shared__ float    s_w[4];

    const int tid = threadIdx.x;
    const int bid = blockIdx.x;
    const int nt  = 3 + (bid < (NTILE - 3 * PBLK) ? 1 : 0);   // first 64 get 4

    float acc = 0.f;

    // prefetch registers (live across compute)
    float4 r0, r1, r2, r3, gtr;
    unsigned labbit = 0u;
    unsigned g_img = NIMG;

#define STAGE_ISSUE(base_) do {                                               \
    const float4* asrc_ = reinterpret_cast<const float4*>(outputs)            \
                        + (size_t)(base_) * 30 / 4;                           \
    r0 = asrc_[tid];                                                          \
    r1 = asrc_[tid + 256];                                                    \
    r2 = asrc_[tid + 512];                                                    \
    if (tid < 192) r3 = asrc_[tid + 768];                                     \
    const unsigned il_ = (base_) / NCELL;                                     \
    if (tid < 128) {                                                          \
        const unsigned g_ = (unsigned)tid >> 5;                               \
        g_img = il_ + g_;                                                     \
        if (g_img < NIMG)                                                     \
            gtr = reinterpret_cast<const float4*>(gt_boxes)[g_img * NGT + (tid & 31)]; \
    } else {                                                                  \
        const int t_ = tid - 128;                                             \
        const unsigned g_ = (unsigned)t_ >> 5;                                \
        g_img = il_ + g_;                                                     \
        labbit = (g_img < NIMG) ? (1u << gt_labels[g_img * NGT + (t_ & 31)])  \
                                : 0u;                                         \
    }                                                                         \
} while (0)

#define STAGE_WRITE(nb_) do {                                                 \
    s_act4[nb_][tid]       = r0;                                              \
    s_act4[nb_][tid + 256] = r1;                                              \
    s_act4[nb_][tid + 512] = r2;                                              \
    if (tid < 192) s_act4[nb_][tid + 768] = r3;                               \
    if (tid < 128) {                                                          \
        if (g_img < NIMG) {                                                   \
            const float gx1 = fmaf(gtr.z, -0.5f, gtr.x);                      \
            const float gy1 = fmaf(gtr.w, -0.5f, gtr.y);                      \
            const float gx2 = fmaf(gtr.z,  0.5f, gtr.x);                      \
            const float gy2 = fmaf(gtr.w,  0.5f, gtr.y);                      \
            s_gtc[nb_][tid] = make_float4(gx1, gy1, gx2, gy2);                \
            h2 mn_; mn_.x = (_Float16)gx1; mn_.y = (_Float16)gy1;             \
            h2 mx_; mx_.x = (_Float16)gx2; mx_.y = (_Float16)gy2;             \
            s_gtp[nb_][tid] = make_uint2(__builtin_bit_cast(unsigned, mn_),   \
                                         __builtin_bit_cast(unsigned, mx_));  \
            s_gah[nb_][tid] = (_Float16)(gtr.z * gtr.w);                      \
        }                                                                     \
    } else {                                                                  \
        unsigned m_ = labbit;                                                 \
        m_ |= __shfl_xor(m_, 1, 32);                                          \
        m_ |= __shfl_xor(m_, 2, 32);                                          \
        m_ |= __shfl_xor(m_, 4, 32);                                          \
        m_ |= __shfl_xor(m_, 8, 32);                                          \
        m_ |= __shfl_xor(m_, 16, 32);                                         \
        const int t_ = tid - 128;                                             \
        if ((t_ & 31) == 0) s_mask[nb_][t_ >> 5] = m_;                        \
    }                                                                         \
} while (0)

    // ---- prologue: stage first tile into buffer 0 ----
    STAGE_ISSUE((unsigned)bid * CPB);
    STAGE_WRITE(0);
    __syncthreads();

    int cur = 0;
    for (int k = 0; k < nt; ++k) {
        const unsigned tile = (unsigned)bid + (unsigned)k * PBLK;
        const unsigned base = tile * CPB;
        const bool hn = (k + 1 < nt);
        if (hn) STAGE_ISSUE((tile + PBLK) * CPB);

        // ================= compute tile from buf[cur] ======================
        const unsigned img_lo = base / NCELL;
        const unsigned off    = base - img_lo * NCELL;       // 0..48

        const int p = tid & 1;
        const int s = tid >> 1;
        const unsigned rel  = ((unsigned)(s + off) * 1339u) >> 16;  // /49
        const unsigned mask = s_mask[cur][rel];
        const float2* a2 = reinterpret_cast<const float2*>(s_act4[cur]) + s * 15;

        // CE, split across the box pair (each thread: 10 classes) — f32 exact
        const float2* cp = a2 + 5 + p * 5;
        float2 c0 = cp[0], c1 = cp[1], c2 = cp[2], c3 = cp[3], c4 = cp[4];
        float mxh = fmaxf(fmaxf(fmaxf(c0.x, c0.y), fmaxf(c1.x, c1.y)),
                          fmaxf(fmaxf(c2.x, c2.y), fmaxf(c3.x, c3.y)));
        mxh = fmaxf(mxh, fmaxf(c4.x, c4.y));
        const unsigned mh = mask >> (p * 10);
        float selh = ((mh & 1u)   ? c0.x : 0.f) + ((mh & 2u)   ? c0.y : 0.f)
                   + ((mh & 4u)   ? c1.x : 0.f) + ((mh & 8u)   ? c1.y : 0.f)
                   + ((mh & 16u)  ? c2.x : 0.f) + ((mh & 32u)  ? c2.y : 0.f)
                   + ((mh & 64u)  ? c3.x : 0.f) + ((mh & 128u) ? c3.y : 0.f)
                   + ((mh & 256u) ? c4.x : 0.f) + ((mh & 512u) ? c4.y : 0.f);
        const float mx = fmaxf(mxh, __shfl_xor(mxh, 1));
        float ssh = __expf(c0.x - mx) + __expf(c0.y - mx)
                  + __expf(c1.x - mx) + __expf(c1.y - mx)
                  + __expf(c2.x - mx) + __expf(c2.y - mx)
                  + __expf(c3.x - mx) + __expf(c3.y - mx)
                  + __expf(c4.x - mx) + __expf(c4.y - mx);
        const float ssum = ssh + __shfl_xor(ssh, 1);
        const float sel  = selh + __shfl_xor(selh, 1);
        const float ce = (float)__popc(mask) * (mx + __logf(ssum)) - sel;

        // my box: floats [5p .. 5p+4] (f32 for epilogue)
        float2 A = a2[2 * p], Bv = a2[2 * p + 1], Cv = a2[2 * p + 2];
        const float cx = p ? A.y  : A.x;
        const float cy = p ? Bv.x : A.y;
        const float w  = p ? Bv.y : Bv.x;
        const float h  = p ? Cv.x : Bv.y;
        const float cf = p ? Cv.y : Cv.x;

        // packed fp16 box geometry
        h2 pmn, pmx;
        pmn.x = (_Float16)fmaf(w, -0.5f, cx); pmn.y = (_Float16)fmaf(h, -0.5f, cy);
        pmx.x = (_Float16)fmaf(w,  0.5f, cx); pmx.y = (_Float16)fmaf(h,  0.5f, cy);
        const _Float16 pae = (_Float16)(w * h + EPS_IOU);

        // IoU argmax over 32 GTs: packed-fp16 geometry, fp16 S-form compare
        const uint4* gtp4 = reinterpret_cast<const uint4*>(s_gtp[cur] + rel * NGT);
        const h2*    gah2 = reinterpret_cast<const h2*>(s_gah[cur] + rel * NGT);
        _Float16 bin = (_Float16)(-1.0f), bS = (_Float16)(1.0f);
        int bi = 0;
        #pragma unroll
        for (int i = 0; i < NGT / 2; ++i) {
            const uint4 rec = gtp4[i];            // {mn0,mx0,mn1,mx1}
            const h2 gap = gah2[i];               // areas (2i, 2i+1)
            {
                h2 lo = H2MAX(pmn, __builtin_bit_cast(h2, rec.x));
                h2 hi = H2MIN(pmx, __builtin_bit_cast(h2, rec.y));
                h2 d  = hi - lo;
                d = H2MAX(d, (h2)((_Float16)0));
                const _Float16 in = d.x * d.y;
                const _Float16 S  = pae + gap.x;
                if (in * bS > bin * S) { bin = in; bS = S; bi = 2 * i; }
            }
            {
                h2 lo = H2MAX(pmn, __builtin_bit_cast(h2, rec.z));
                h2 hi = H2MIN(pmx, __builtin_bit_cast(h2, rec.w));
                h2 d  = hi - lo;
                d = H2MAX(d, (h2)((_Float16)0));
                const _Float16 in = d.x * d.y;
                const _Float16 S  = pae + gap.y;
                if (in * bS > bin * S) { bin = in; bS = S; bi = 2 * i + 1; }
            }
        }

        // epilogue: f32 exact loc/conf from the f32 corner table
        float term;
        if ((float)bin > 0.f) {
            float4 g = s_gtc[cur][rel * NGT + bi];
            const float binf = (float)bin, bSf = (float)bS;
            const float iou = __fdividef(binf, bSf - binf);
            const float dx = cx - (g.x + g.z) * 0.5f;
            const float dy = cy - (g.y + g.w) * 0.5f;
            const float dw = sqrtf(w) - sqrtf(g.z - g.x);
            const float dh = sqrtf(h) - sqrtf(g.w - g.y);
            term = LAMBDA_COORD * (dx * dx + dy * dy + dw * dw + dh * dh)
                 + (cf - iou) * (cf - iou) + ce;
        } else {
            term = LAMBDA_NOOBJ * cf * cf;
        }
        acc += term;
        // ===================================================================

        if (hn) STAGE_WRITE(cur ^ 1);
        __syncthreads();
        cur ^= 1;
    }

    // ---- block reduce -> 1 float per block ----
    #pragma unroll
    for (int o = 32; o > 0; o >>= 1)
        acc += __shfl_down(acc, o);
    if ((tid & 63) == 0) s_w[tid >> 6] = acc;
    __syncthreads();
    if (tid == 0)
        partials[bid] = s_w[0] + s_w[1] + s_w[2] + s_w[3];
}

__global__ __launch_bounds__(256) void yolo_reduce_kernel(
    const float* __restrict__ partials, float* __restrict__ out)
{
    float s = 0.f;
    #pragma unroll
    for (int k = 0; k < PBLK / 256; ++k)
        s += partials[threadIdx.x + k * 256];
    #pragma unroll
    for (int o = 32; o > 0; o >>= 1)
        s += __shfl_down(s, o);
    __shared__ float s_w[4];
    const int tid = threadIdx.x;
    if ((tid & 63) == 0) s_w[tid >> 6] = s;
    __syncthreads();
    if (tid == 0)
        out[0] = (s_w[0] + s_w[1] + s_w[2] + s_w[3]) * (1.0f / (float)NIMG);
}

extern "C" void kernel_launch(void* const* d_in, const int* in_sizes, int n_in,
                              void* d_out, int out_size, void* d_ws, size_t ws_size,
                              hipStream_t stream) {
    const float* outputs   = (const float*)d_in[0];
    const float* gt_boxes  = (const float*)d_in[1];
    const int*   gt_labels = (const int*)d_in[2];
    float* out      = (float*)d_out;
    float* partials = (float*)d_ws;          // PBLK floats = 4 KB

    yolo_main_kernel<<<PBLK, 256, 0, stream>>>(outputs, gt_boxes, gt_labels, partials);
    yolo_reduce_kernel<<<1, 256, 0, stream>>>(partials, out);
}